// Round 10
// baseline (222.791 us; speedup 1.0000x reference)
//
#include <hip/hip_runtime.h>

typedef __bf16 bf16;
typedef __attribute__((ext_vector_type(4))) __bf16 bf16x4;
typedef __attribute__((ext_vector_type(8))) __bf16 bf16x8;
typedef __attribute__((ext_vector_type(4))) float f32x4;

static __device__ __forceinline__ f32x4 mfma_16x16x32(bf16x8 a, bf16x8 b, f32x4 c) {
    return __builtin_amdgcn_mfma_f32_16x16x32_bf16(a, b, c, 0, 0, 0);
}

static __device__ __forceinline__ bf16x8 load8(const float* p) {
    f32x4 a = *(const f32x4*)p;
    f32x4 b = *(const f32x4*)(p + 4);
    bf16x8 r;
    r[0] = (bf16)a[0]; r[1] = (bf16)a[1]; r[2] = (bf16)a[2]; r[3] = (bf16)a[3];
    r[4] = (bf16)b[0]; r[5] = (bf16)b[1]; r[6] = (bf16)b[2]; r[7] = (bf16)b[3];
    return r;
}

// async global->LDS, 16B per lane; LDS dest = wave-uniform base + lane*16
static __device__ __forceinline__ void gload_lds16(const void* g, void* l) {
    __builtin_amdgcn_global_load_lds(
        (const __attribute__((address_space(1))) void*)g,
        (__attribute__((address_space(3))) void*)l, 16, 0, 0);
}

// Q pre-scale: (1/sqrt(1024)) * log2(e)  -> softmax via raw v_exp_f32 (2^x)
#define QSCALE 0.0450842200277801f

// Counted-vmcnt sync bundle (R3-verified)
#define SYNC_PRE(N)                                                      \
    do {                                                                 \
        asm volatile("s_waitcnt vmcnt(" #N ")" ::: "memory");            \
        __builtin_amdgcn_s_barrier();                                    \
        __builtin_amdgcn_sched_barrier(0);                               \
    } while (0)

#define SYNC_POST()                                                     \
    do {                                                                \
        asm volatile("s_waitcnt lgkmcnt(0)" ::: "memory");              \
        __builtin_amdgcn_sched_barrier(0);                              \
        __builtin_amdgcn_s_barrier();                                   \
    } while (0)

// ---------------------------------------------------------------------------
// Prep: fused elementwise casts (l_h, v_h -> bf16) + 4 weight
// transpose-converts (f32 (K,N) -> bf16 (N,K)). q-weight pre-scaled.
// ---------------------------------------------------------------------------
__global__ __launch_bounds__(256) void prep_kernel(
    const float* __restrict__ l_h, const float* __restrict__ v_h,
    const float* __restrict__ w0, const float* __restrict__ w1,
    const float* __restrict__ w2, const float* __restrict__ w3,
    bf16* __restrict__ l_bf, bf16* __restrict__ v_bf,
    bf16* __restrict__ dq, bf16* __restrict__ dkv, bf16* __restrict__ dov)
{
    const int id = blockIdx.x;
    if (id < 4096) {
        const float* s = (id < 2048) ? l_h : v_h;
        bf16*       d = (id < 2048) ? l_bf : v_bf;
        const int   bb = (id < 2048) ? id : id - 2048;
        const size_t i = ((size_t)bb * 256 + threadIdx.x) * 8;
        *(bf16x8*)(d + i) = load8(s + i);
        return;
    }
    const int widx = id - 4096;
    const int z    = widx >> 8;
    const int rem  = widx & 255;
    const int j0   = (rem & 15) * 64;    // n tile
    const int i0   = (rem >> 4) * 64;    // k tile
    const float* src; bf16* dst;
    switch (z) {
        case 0:  src = w0; dst = dq; break;
        case 1:  src = w1; dst = dkv; break;
        case 2:  src = w2; dst = dkv + (size_t)1024 * 1024; break;
        default: src = w3; dst = dov; break;
    }
    const float wscale = (z == 0) ? QSCALE : 1.0f;
    __shared__ float T[64][65];
    const int tx = threadIdx.x & 15;
    const int ty = threadIdx.x >> 4;
    #pragma unroll
    for (int it = 0; it < 4; ++it) {
        f32x4 v = *(const f32x4*)(src + (size_t)(i0 + ty + it * 16) * 1024 + j0 + tx * 4);
        T[ty + it * 16][tx * 4 + 0] = v[0];
        T[ty + it * 16][tx * 4 + 1] = v[1];
        T[ty + it * 16][tx * 4 + 2] = v[2];
        T[ty + it * 16][tx * 4 + 3] = v[3];
    }
    __syncthreads();
    #pragma unroll
    for (int it = 0; it < 4; ++it) {
        const int jj = ty + it * 16;
        bf16x4 o;
        o[0] = (bf16)(T[tx * 4 + 0][jj] * wscale);
        o[1] = (bf16)(T[tx * 4 + 1][jj] * wscale);
        o[2] = (bf16)(T[tx * 4 + 2][jj] * wscale);
        o[3] = (bf16)(T[tx * 4 + 3][jj] * wscale);
        *(bf16x4*)(dst + (size_t)(j0 + jj) * 1024 + i0 + tx * 4) = o;
    }
}

// ---------------------------------------------------------------------------
// Fused Q+KV projection, 128x128 tile. R3-VERIFIED (43.8us): triple-buffered
// LDS, prefetch 2 K-steps ahead, counted vmcnt(8), raw s_barrier, XCD-chunked
// swizzle. grid 768: bx<8 -> Q, bx>=8 -> KV. LDS 48KB -> 3 blocks/CU.
// ---------------------------------------------------------------------------
__global__ __launch_bounds__(256, 3) void proj128_kernel(
    const bf16* __restrict__ l_bf, const bf16* __restrict__ v_bf,
    const bf16* __restrict__ QWt,  const bf16* __restrict__ KVWt,
    const float* __restrict__ q_b, const float* __restrict__ k_b,
    const float* __restrict__ v_b,
    bf16* __restrict__ Qh, bf16* __restrict__ Kh, bf16* __restrict__ Vt)
{
    __shared__ __align__(16) bf16 As[3][128][32];
    __shared__ __align__(16) bf16 Bs[3][128][32];

    const int t    = threadIdx.x;
    const int lane = t & 63;
    const int wave = t >> 6;
    const int wm   = wave & 1;
    const int wn   = wave >> 1;
    const int l15  = lane & 15;
    const int quad = lane >> 4;

    // XCD-chunked swizzle (bijective: 768 % 8 == 0, chunk = 96)
    const int orig = blockIdx.y * 24 + blockIdx.x;
    const int wg   = (orig & 7) * 96 + (orig >> 3);
    const int by   = wg / 24;
    const int bx   = wg - by * 24;

    const bool isQ = bx < 8;
    const bf16* A  = isQ ? l_bf : v_bf;
    const bf16* Bt = isQ ? QWt  : KVWt;
    const int  gn0 = (isQ ? bx : bx - 8) * 128;
    const int  gm0 = by * 128;
    const int  K   = 1024;

    const int srow    = lane >> 2;
    const int chunk_g = (lane & 3) ^ ((srow >> 1) & 3);
    const size_t aoff = (size_t)(gm0 + wave * 32 + srow) * K + chunk_g * 8;
    const size_t boff = (size_t)(gn0 + wave * 32 + srow) * K + chunk_g * 8;

    f32x4 acc[4][4];
    #pragma unroll
    for (int i = 0; i < 4; ++i)
        #pragma unroll
        for (int j = 0; j < 4; ++j)
            acc[i][j] = (f32x4){0.f, 0.f, 0.f, 0.f};

    #define PSTAGE(k0_, buf_)                                                      \
        {                                                                          \
            _Pragma("unroll")                                                      \
            for (int q = 0; q < 2; ++q) {                                          \
                gload_lds16(A  + aoff + (size_t)q * 16 * K + (k0_),                \
                            &As[buf_][wave * 32 + q * 16][0]);                     \
                gload_lds16(Bt + boff + (size_t)q * 16 * K + (k0_),                \
                            &Bs[buf_][wave * 32 + q * 16][0]);                     \
            }                                                                      \
        }

    #define PCOMPUTE(bufi)                                                         \
        {                                                                          \
            bf16x8 af[4], bfr[4];                                                  \
            _Pragma("unroll")                                                      \
            for (int mt = 0; mt < 4; ++mt) {                                       \
                const int row = wm * 64 + mt * 16 + l15;                           \
                af[mt] = *(const bf16x8*)(&As[bufi][row][(quad ^ ((row >> 1) & 3)) * 8]); \
            }                                                                      \
            _Pragma("unroll")                                                      \
            for (int nt = 0; nt < 4; ++nt) {                                       \
                const int row = wn * 64 + nt * 16 + l15;                           \
                bfr[nt] = *(const bf16x8*)(&Bs[bufi][row][(quad ^ ((row >> 1) & 3)) * 8]); \
            }                                                                      \
            __builtin_amdgcn_s_setprio(1);                                         \
            _Pragma("unroll")                                                      \
            for (int mt = 0; mt < 4; ++mt)                                         \
                _Pragma("unroll")                                                  \
                for (int nt = 0; nt < 4; ++nt)                                     \
                    acc[mt][nt] = mfma_16x16x32(af[mt], bfr[nt], acc[mt][nt]);     \
            __builtin_amdgcn_s_setprio(0);                                         \
        }

    PSTAGE(0, 0);            // 4 in flight
    PSTAGE(32, 1);           // 8 in flight
    int bc = 0, bn2 = 2;     // compute buffer / stage-target buffer (t+2)

    for (int k0 = 0; k0 < K - 64; k0 += 32) {
        PSTAGE(k0 + 64, bn2);        // 12 in flight
        SYNC_PRE(8);                 // oldest 4 (buf bc) landed; 8 stay in flight
        PCOMPUTE(bc);
        SYNC_POST();                 // all waves done reading bc -> overwritable
        int nb = bc + 1;  if (nb == 3) nb = 0;
        int nn = bn2 + 1; if (nn == 3) nn = 0;
        bc = nb; bn2 = nn;
    }
    SYNC_PRE(4);                     // tail: K-64 tile
    PCOMPUTE(bc);
    SYNC_POST();
    bc = (bc + 1 == 3) ? 0 : bc + 1;
    SYNC_PRE(0);                     // tail: K-32 tile
    PCOMPUTE(bc);

    #undef PSTAGE
    #undef PCOMPUTE

    #pragma unroll
    for (int nt = 0; nt < 4; ++nt) {
        const int col = gn0 + wn * 64 + nt * 16 + l15;
        float bb; bf16* dst; bool hm;
        if (isQ)             { bb = q_b[col] * QSCALE;   dst = Qh; hm = true;  }
        else if (col < 1024) { bb = k_b[col];            dst = Kh; hm = true;  }
        else                 { bb = v_b[col - 1024];     dst = Vt; hm = false; }
        #pragma unroll
        for (int mt = 0; mt < 4; ++mt) {
            #pragma unroll
            for (int r = 0; r < 4; ++r) {
                const int row = gm0 + wm * 64 + mt * 16 + quad * 4 + r;
                const float v = acc[mt][nt][r] + bb;
                if (hm) {
                    const size_t idx =
                        ((size_t)((row >> 10) * 16 + (col >> 6)) * 1024 +
                         (row & 1023)) * 64 + (col & 63);
                    dst[idx] = (bf16)v;
                } else {
                    const int vc = col - 1024;
                    const size_t idx =
                        ((size_t)((row >> 10) * 16 + (vc >> 6)) * 64 +
                         (vc & 63)) * 1024 + (row & 1023);
                    dst[idx] = (bf16)v;
                }
            }
        }
    }
}

// ---------------------------------------------------------------------------
// Output projection: 128x64 tile (BK=32, 4 waves 2x2, acc 4x2),
// triple-buffer counted-vmcnt schedule (R3-verified). XCD swizzle.
// ---------------------------------------------------------------------------
__global__ __launch_bounds__(256, 3) void ogemm_kernel(
    const bf16* __restrict__ Aw, const bf16* __restrict__ OWt,
    const float* __restrict__ o_b, float* __restrict__ C)
{
    __shared__ __align__(16) bf16 As[3][128][32];
    __shared__ __align__(16) bf16 Bs[3][64][32];

    const int t    = threadIdx.x;
    const int lane = t & 63;
    const int wave = t >> 6;
    const int wm   = wave & 1;
    const int wn   = wave >> 1;
    const int l15  = lane & 15;
    const int quad = lane >> 4;

    const int orig = blockIdx.y * 16 + blockIdx.x;
    const int wg   = (orig & 7) * 64 + (orig >> 3);
    const int by   = wg >> 4;
    const int bx   = wg & 15;

    const int gn0 = bx * 64;
    const int gm0 = by * 128;
    const int K   = 1024;

    const int srow    = lane >> 2;
    const int chunk_g = (lane & 3) ^ ((srow >> 1) & 3);
    const size_t aoff = (size_t)(gm0 + wave * 32 + srow) * K + chunk_g * 8;
    const size_t boff = (size_t)(gn0 + wave * 16 + srow) * K + chunk_g * 8;

    f32x4 acc[4][2];
    #pragma unroll
    for (int i = 0; i < 4; ++i)
        #pragma unroll
        for (int j = 0; j < 2; ++j)
            acc[i][j] = (f32x4){0.f, 0.f, 0.f, 0.f};

    #define OSTAGE(k0_, buf_)                                                          \
        {                                                                              \
            gload_lds16(Aw + aoff + (k0_),                  &As[buf_][wave * 32][0]);  \
            gload_lds16(Aw + aoff + (size_t)16 * K + (k0_), &As[buf_][wave * 32 + 16][0]); \
            gload_lds16(OWt + boff + (k0_),                 &Bs[buf_][wave * 16][0]);  \
        }

    #define OCOMPUTE(bufi)                                                             \
        {                                                                              \
            bf16x8 af[4], bfr[2];                                                      \
            _Pragma("unroll")                                                          \
            for (int mt = 0; mt < 4; ++mt) {                                           \
                const int row = wm * 64 + mt * 16 + l15;                               \
                af[mt] = *(const bf16x8*)(&As[bufi][row][(quad ^ ((row >> 1) & 3)) * 8]); \
            }                                                                          \
            _Pragma("unroll")                                                          \
            for (int nt = 0; nt < 2; ++nt) {                                           \
                const int row = wn * 32 + nt * 16 + l15;                               \
                bfr[nt] = *(const bf16x8*)(&Bs[bufi][row][(quad ^ ((row >> 1) & 3)) * 8]); \
            }                                                                          \
            __builtin_amdgcn_s_setprio(1);                                             \
            _Pragma("unroll")                                                          \
            for (int mt = 0; mt < 4; ++mt)                                             \
                _Pragma("unroll")                                                      \
                for (int nt = 0; nt < 2; ++nt)                                         \
                    acc[mt][nt] = mfma_16x16x32(af[mt], bfr[nt], acc[mt][nt]);         \
            __builtin_amdgcn_s_setprio(0);                                             \
        }

    OSTAGE(0, 0);
    OSTAGE(32, 1);
    int bc = 0, bn2 = 2;

    for (int k0 = 0; k0 < K - 64; k0 += 32) {
        OSTAGE(k0 + 64, bn2);
        SYNC_PRE(6);
        OCOMPUTE(bc);
        SYNC_POST();
        int nb = bc + 1;  if (nb == 3) nb = 0;
        int nn = bn2 + 1; if (nn == 3) nn = 0;
        bc = nb; bn2 = nn;
    }
    SYNC_PRE(3);
    OCOMPUTE(bc);
    SYNC_POST();
    bc = (bc + 1 == 3) ? 0 : bc + 1;
    SYNC_PRE(0);
    OCOMPUTE(bc);

    #undef OSTAGE
    #undef OCOMPUTE

    #pragma unroll
    for (int nt = 0; nt < 2; ++nt) {
        const int col = gn0 + wn * 32 + nt * 16 + l15;
        const float bb = o_b[col];
        #pragma unroll
        for (int mt = 0; mt < 4; ++mt) {
            #pragma unroll
            for (int r = 0; r < 4; ++r) {
                const int row = gm0 + wm * 64 + mt * 16 + quad * 4 + r;
                C[(size_t)row * 1024 + col] = acc[mt][nt][r] + bb;
            }
        }
    }
}

// ---------------------------------------------------------------------------
// Attention v9: QBLK=128 (R3 geometry, 32 q-rows/wave) with K/V LDS STAGING
// REMOVED -- K/V per head is 256KB (L2-resident; R8 FETCH confirms), so
// staging was pure overhead (m169 regime: VALUBusy 33% on gload issue,
// MfmaUtil 16%). Fragments read direct from global; swizzle algebra
// collapses (staged value == Kp[(kv0+row)*64 + quad*8] etc.), so MFMA
// operands are bit-identical to the verified R3 kernel. No barriers at all;
// waves independent; LDS = per-wave P only (18KB).
// ---------------------------------------------------------------------------
__global__ __launch_bounds__(256) void attn_kernel(
    const bf16* __restrict__ Q, const bf16* __restrict__ K,
    const bf16* __restrict__ V, bf16* __restrict__ O)
{
    const int t    = threadIdx.x;
    const int lane = t & 63;
    const int wave = t >> 6;
    const int l15  = lane & 15;
    const int quad = lane >> 4;

    const int head = blockIdx.x;        // b*16 + h
    const int q0   = blockIdx.y * 128;
    const int b    = head >> 4;
    const int h    = head & 15;

    __shared__ __align__(16) bf16 P[4][32][72];    // per-wave P, pad 64->72

    const bf16* Qp  = Q + ((size_t)head * 1024 + q0 + wave * 32) * 64;
    const bf16* Kp  = K + (size_t)head * 1024 * 64;
    const bf16* Vtp = V + (size_t)head * 64 * 1024;

    bf16x8 aq[2][2];
    #pragma unroll
    for (int mt = 0; mt < 2; ++mt)
        #pragma unroll
        for (int kc = 0; kc < 2; ++kc)
            aq[mt][kc] = *(const bf16x8*)(Qp + (mt * 16 + l15) * 64 + kc * 32 + quad * 8);

    bf16x8 vones;
    #pragma unroll
    for (int j = 0; j < 8; ++j) vones[j] = (bf16)1.0f;

    f32x4 oacc[2][4];
    #pragma unroll
    for (int mt = 0; mt < 2; ++mt)
        #pragma unroll
        for (int nt = 0; nt < 4; ++nt)
            oacc[mt][nt] = (f32x4){0.f, 0.f, 0.f, 0.f};
    f32x4 lacc[2];
    lacc[0] = (f32x4){0.f, 0.f, 0.f, 0.f};
    lacc[1] = (f32x4){0.f, 0.f, 0.f, 0.f};

    #pragma unroll 2
    for (int c = 0; c < 16; ++c) {
        const int kv0 = c * 64;

        #pragma unroll
        for (int nt = 0; nt < 4; ++nt) {
            const bf16* krow = Kp + (size_t)(kv0 + nt * 16 + l15) * 64;
            bf16x8 bk0 = *(const bf16x8*)(krow + quad * 8);
            bf16x8 bk1 = *(const bf16x8*)(krow + 32 + quad * 8);
            #pragma unroll
            for (int mt = 0; mt < 2; ++mt) {
                f32x4 s = (f32x4){0.f, 0.f, 0.f, 0.f};
                s = mfma_16x16x32(aq[mt][0], bk0, s);
                s = mfma_16x16x32(aq[mt][1], bk1, s);
                #pragma unroll
                for (int r = 0; r < 4; ++r) {
                    const float e = __builtin_amdgcn_exp2f(s[r]);
                    P[wave][mt * 16 + quad * 4 + r][nt * 16 + l15] = (bf16)e;
                }
            }
        }

        #pragma unroll
        for (int mt = 0; mt < 2; ++mt) {
            bf16x8 pa0 = *(const bf16x8*)(&P[wave][mt * 16 + l15][quad * 8]);
            bf16x8 pa1 = *(const bf16x8*)(&P[wave][mt * 16 + l15][32 + quad * 8]);
            lacc[mt] = mfma_16x16x32(pa0, vones, lacc[mt]);
            lacc[mt] = mfma_16x16x32(pa1, vones, lacc[mt]);
            #pragma unroll
            for (int nt = 0; nt < 4; ++nt) {
                const bf16* vrow = Vtp + (size_t)(nt * 16 + l15) * 1024 + kv0;
                bf16x8 bv0 = *(const bf16x8*)(vrow + quad * 8);
                bf16x8 bv1 = *(const bf16x8*)(vrow + 32 + quad * 8);
                oacc[mt][nt] = mfma_16x16x32(pa0, bv0, oacc[mt][nt]);
                oacc[mt][nt] = mfma_16x16x32(pa1, bv1, oacc[mt][nt]);
            }
        }
    }

    // lacc[mt][r] = row sum for row quad*4+r, replicated across all 16 cols
    #pragma unroll
    for (int mt = 0; mt < 2; ++mt) {
        const float invs[4] = {1.0f / lacc[mt][0], 1.0f / lacc[mt][1],
                               1.0f / lacc[mt][2], 1.0f / lacc[mt][3]};
        #pragma unroll
        for (int nt = 0; nt < 4; ++nt) {
            #pragma unroll
            for (int r = 0; r < 4; ++r) {
                const int row = q0 + wave * 32 + mt * 16 + quad * 4 + r;
                O[((size_t)b * 1024 + row) * 1024 + h * 64 + nt * 16 + l15] =
                    (bf16)(oacc[mt][nt][r] * invs[r]);
            }
        }
    }
}

// ---------------------------------------------------------------------------
// Host launcher — inputs/outputs FLOAT32 per reference; bf16 internal.
// ws (bf16 elems): l_bf 4M | v_bf 4M | QWt 1M | KVWt 2M | OWt 1M |
//                  Qh 4M | Kh 4M | Vt 4M | Aw 4M = 28M = 56 MB
// ---------------------------------------------------------------------------
extern "C" void kernel_launch(void* const* d_in, const int* in_sizes, int n_in,
                              void* d_out, int out_size, void* d_ws, size_t ws_size,
                              hipStream_t stream)
{
    const float* v_h = (const float*)d_in[0];
    const float* l_h = (const float*)d_in[1];
    const float* q_w = (const float*)d_in[2];
    const float* q_b = (const float*)d_in[3];
    const float* k_w = (const float*)d_in[4];
    const float* k_b = (const float*)d_in[5];
    const float* v_w = (const float*)d_in[6];
    const float* v_b = (const float*)d_in[7];
    const float* o_w = (const float*)d_in[8];
    const float* o_b = (const float*)d_in[9];
    float* out = (float*)d_out;

    const size_t SZ = (size_t)4096 * 1024;      // 4M
    const size_t WZ = (size_t)1024 * 1024;      // 1M

    bf16* l_bf = (bf16*)d_ws;
    bf16* v_bf = l_bf + SZ;
    bf16* QWt  = v_bf + SZ;
    bf16* KVWt = QWt + WZ;
    bf16* OWt  = KVWt + 2 * WZ;
    bf16* Qh   = OWt + WZ;      // (b,h,ls,64), pre-scaled by QSCALE
    bf16* Kh   = Qh + SZ;       // (b,h,vs,64)
    bf16* Vt   = Kh + SZ;       // (b,h,64,vs)
    bf16* Aw   = Vt + SZ;       // (b,ls,1024)

    prep_kernel<<<dim3(5120), 256, 0, stream>>>(
        l_h, v_h, q_w, k_w, v_w, o_w, l_bf, v_bf, QWt, KVWt, OWt);

    proj128_kernel<<<dim3(24, 32), 256, 0, stream>>>(
        l_bf, v_bf, QWt, KVWt, q_b, k_b, v_b, Qh, Kh, Vt);

    attn_kernel<<<dim3(64, 8), 256, 0, stream>>>(Qh, Kh, Vt, Aw);

    ogemm_kernel<<<dim3(16, 32), 256, 0, stream>>>(Aw, OWt, o_b, out);

    (void)in_sizes; (void)n_in; (void)out_size; (void)ws_size;
}

// Round 11
// 189.687 us; speedup vs baseline: 1.1745x; 1.1745x over previous
//
#include <hip/hip_runtime.h>

typedef __bf16 bf16;
typedef __attribute__((ext_vector_type(4))) __bf16 bf16x4;
typedef __attribute__((ext_vector_type(8))) __bf16 bf16x8;
typedef __attribute__((ext_vector_type(4))) float f32x4;

static __device__ __forceinline__ f32x4 mfma_16x16x32(bf16x8 a, bf16x8 b, f32x4 c) {
    return __builtin_amdgcn_mfma_f32_16x16x32_bf16(a, b, c, 0, 0, 0);
}

static __device__ __forceinline__ bf16x8 load8(const float* p) {
    f32x4 a = *(const f32x4*)p;
    f32x4 b = *(const f32x4*)(p + 4);
    bf16x8 r;
    r[0] = (bf16)a[0]; r[1] = (bf16)a[1]; r[2] = (bf16)a[2]; r[3] = (bf16)a[3];
    r[4] = (bf16)b[0]; r[5] = (bf16)b[1]; r[6] = (bf16)b[2]; r[7] = (bf16)b[3];
    return r;
}

// async global->LDS, 16B per lane; LDS dest = wave-uniform base + lane*16
static __device__ __forceinline__ void gload_lds16(const void* g, void* l) {
    __builtin_amdgcn_global_load_lds(
        (const __attribute__((address_space(1))) void*)g,
        (__attribute__((address_space(3))) void*)l, 16, 0, 0);
}

// Q pre-scale: (1/sqrt(1024)) * log2(e)  -> softmax via raw v_exp_f32 (2^x)
#define QSCALE 0.0450842200277801f

// Counted-vmcnt sync bundle (T4): wait only the OLDEST tile's loads; raw
// s_barrier does NOT drain vmcnt (unlike __syncthreads). sched_barrier(0)
// pins ds_reads between the barriers (prevents m152-style sink races).
#define SYNC_PRE(N)                                                      \
    do {                                                                 \
        asm volatile("s_waitcnt vmcnt(" #N ")" ::: "memory");            \
        __builtin_amdgcn_s_barrier();                                    \
        __builtin_amdgcn_sched_barrier(0);                               \
    } while (0)

#define SYNC_POST()                                                     \
    do {                                                                \
        asm volatile("s_waitcnt lgkmcnt(0)" ::: "memory");              \
        __builtin_amdgcn_sched_barrier(0);                              \
        __builtin_amdgcn_s_barrier();                                   \
    } while (0)

// ---------------------------------------------------------------------------
// Prep: fused elementwise casts (l_h, v_h -> bf16) + 4 weight
// transpose-converts (f32 (K,N) -> bf16 (N,K)). q-weight pre-scaled by
// QSCALE so attn computes 2^s directly (base-2 softmax == base-e).
// ---------------------------------------------------------------------------
__global__ __launch_bounds__(256) void prep_kernel(
    const float* __restrict__ l_h, const float* __restrict__ v_h,
    const float* __restrict__ w0, const float* __restrict__ w1,
    const float* __restrict__ w2, const float* __restrict__ w3,
    bf16* __restrict__ l_bf, bf16* __restrict__ v_bf,
    bf16* __restrict__ dq, bf16* __restrict__ dkv, bf16* __restrict__ dov)
{
    const int id = blockIdx.x;
    if (id < 4096) {
        const float* s = (id < 2048) ? l_h : v_h;
        bf16*       d = (id < 2048) ? l_bf : v_bf;
        const int   bb = (id < 2048) ? id : id - 2048;
        const size_t i = ((size_t)bb * 256 + threadIdx.x) * 8;
        *(bf16x8*)(d + i) = load8(s + i);
        return;
    }
    const int widx = id - 4096;
    const int z    = widx >> 8;
    const int rem  = widx & 255;
    const int j0   = (rem & 15) * 64;    // n tile
    const int i0   = (rem >> 4) * 64;    // k tile
    const float* src; bf16* dst;
    switch (z) {
        case 0:  src = w0; dst = dq; break;
        case 1:  src = w1; dst = dkv; break;
        case 2:  src = w2; dst = dkv + (size_t)1024 * 1024; break;
        default: src = w3; dst = dov; break;
    }
    const float wscale = (z == 0) ? QSCALE : 1.0f;
    __shared__ float T[64][65];
    const int tx = threadIdx.x & 15;
    const int ty = threadIdx.x >> 4;
    #pragma unroll
    for (int it = 0; it < 4; ++it) {
        f32x4 v = *(const f32x4*)(src + (size_t)(i0 + ty + it * 16) * 1024 + j0 + tx * 4);
        T[ty + it * 16][tx * 4 + 0] = v[0];
        T[ty + it * 16][tx * 4 + 1] = v[1];
        T[ty + it * 16][tx * 4 + 2] = v[2];
        T[ty + it * 16][tx * 4 + 3] = v[3];
    }
    __syncthreads();
    #pragma unroll
    for (int it = 0; it < 4; ++it) {
        const int jj = ty + it * 16;
        bf16x4 o;
        o[0] = (bf16)(T[tx * 4 + 0][jj] * wscale);
        o[1] = (bf16)(T[tx * 4 + 1][jj] * wscale);
        o[2] = (bf16)(T[tx * 4 + 2][jj] * wscale);
        o[3] = (bf16)(T[tx * 4 + 3][jj] * wscale);
        *(bf16x4*)(dst + (size_t)(j0 + jj) * 1024 + i0 + tx * 4) = o;
    }
}

// ---------------------------------------------------------------------------
// Fused Q+KV projection, 128x128 tile. R3-VERIFIED (43.8us): triple-buffered
// LDS, prefetch 2 K-steps ahead, counted vmcnt(8), raw s_barrier, XCD-chunked
// swizzle. grid 768: bx<8 -> Q, bx>=8 -> KV. LDS 48KB -> 3 blocks/CU.
// ---------------------------------------------------------------------------
__global__ __launch_bounds__(256, 3) void proj128_kernel(
    const bf16* __restrict__ l_bf, const bf16* __restrict__ v_bf,
    const bf16* __restrict__ QWt,  const bf16* __restrict__ KVWt,
    const float* __restrict__ q_b, const float* __restrict__ k_b,
    const float* __restrict__ v_b,
    bf16* __restrict__ Qh, bf16* __restrict__ Kh, bf16* __restrict__ Vt)
{
    __shared__ __align__(16) bf16 As[3][128][32];
    __shared__ __align__(16) bf16 Bs[3][128][32];

    const int t    = threadIdx.x;
    const int lane = t & 63;
    const int wave = t >> 6;
    const int wm   = wave & 1;
    const int wn   = wave >> 1;
    const int l15  = lane & 15;
    const int quad = lane >> 4;

    // XCD-chunked swizzle (bijective: 768 % 8 == 0, chunk = 96)
    const int orig = blockIdx.y * 24 + blockIdx.x;
    const int wg   = (orig & 7) * 96 + (orig >> 3);
    const int by   = wg / 24;
    const int bx   = wg - by * 24;

    const bool isQ = bx < 8;
    const bf16* A  = isQ ? l_bf : v_bf;
    const bf16* Bt = isQ ? QWt  : KVWt;
    const int  gn0 = (isQ ? bx : bx - 8) * 128;
    const int  gm0 = by * 128;
    const int  K   = 1024;

    const int srow    = lane >> 2;
    const int chunk_g = (lane & 3) ^ ((srow >> 1) & 3);
    const size_t aoff = (size_t)(gm0 + wave * 32 + srow) * K + chunk_g * 8;
    const size_t boff = (size_t)(gn0 + wave * 32 + srow) * K + chunk_g * 8;

    f32x4 acc[4][4];
    #pragma unroll
    for (int i = 0; i < 4; ++i)
        #pragma unroll
        for (int j = 0; j < 4; ++j)
            acc[i][j] = (f32x4){0.f, 0.f, 0.f, 0.f};

    #define PSTAGE(k0_, buf_)                                                      \
        {                                                                          \
            _Pragma("unroll")                                                      \
            for (int q = 0; q < 2; ++q) {                                          \
                gload_lds16(A  + aoff + (size_t)q * 16 * K + (k0_),                \
                            &As[buf_][wave * 32 + q * 16][0]);                     \
                gload_lds16(Bt + boff + (size_t)q * 16 * K + (k0_),                \
                            &Bs[buf_][wave * 32 + q * 16][0]);                     \
            }                                                                      \
        }

    #define PCOMPUTE(bufi)                                                         \
        {                                                                          \
            bf16x8 af[4], bfr[4];                                                  \
            _Pragma("unroll")                                                      \
            for (int mt = 0; mt < 4; ++mt) {                                       \
                const int row = wm * 64 + mt * 16 + l15;                           \
                af[mt] = *(const bf16x8*)(&As[bufi][row][(quad ^ ((row >> 1) & 3)) * 8]); \
            }                                                                      \
            _Pragma("unroll")                                                      \
            for (int nt = 0; nt < 4; ++nt) {                                       \
                const int row = wn * 64 + nt * 16 + l15;                           \
                bfr[nt] = *(const bf16x8*)(&Bs[bufi][row][(quad ^ ((row >> 1) & 3)) * 8]); \
            }                                                                      \
            __builtin_amdgcn_s_setprio(1);                                         \
            _Pragma("unroll")                                                      \
            for (int mt = 0; mt < 4; ++mt)                                         \
                _Pragma("unroll")                                                  \
                for (int nt = 0; nt < 4; ++nt)                                     \
                    acc[mt][nt] = mfma_16x16x32(af[mt], bfr[nt], acc[mt][nt]);     \
            __builtin_amdgcn_s_setprio(0);                                         \
        }

    PSTAGE(0, 0);            // 4 in flight
    PSTAGE(32, 1);           // 8 in flight
    int bc = 0, bn2 = 2;     // compute buffer / stage-target buffer (t+2)

    for (int k0 = 0; k0 < K - 64; k0 += 32) {
        PSTAGE(k0 + 64, bn2);        // 12 in flight
        SYNC_PRE(8);                 // oldest 4 (buf bc) landed; 8 stay in flight
        PCOMPUTE(bc);
        SYNC_POST();                 // all waves done reading bc -> overwritable
        int nb = bc + 1;  if (nb == 3) nb = 0;
        int nn = bn2 + 1; if (nn == 3) nn = 0;
        bc = nb; bn2 = nn;
    }
    SYNC_PRE(4);                     // tail: K-64 tile
    PCOMPUTE(bc);
    SYNC_POST();
    bc = (bc + 1 == 3) ? 0 : bc + 1;
    SYNC_PRE(0);                     // tail: K-32 tile
    PCOMPUTE(bc);

    #undef PSTAGE
    #undef PCOMPUTE

    #pragma unroll
    for (int nt = 0; nt < 4; ++nt) {
        const int col = gn0 + wn * 64 + nt * 16 + l15;
        float bb; bf16* dst; bool hm;
        if (isQ)             { bb = q_b[col] * QSCALE;   dst = Qh; hm = true;  }
        else if (col < 1024) { bb = k_b[col];            dst = Kh; hm = true;  }
        else                 { bb = v_b[col - 1024];     dst = Vt; hm = false; }
        #pragma unroll
        for (int mt = 0; mt < 4; ++mt) {
            #pragma unroll
            for (int r = 0; r < 4; ++r) {
                const int row = gm0 + wm * 64 + mt * 16 + quad * 4 + r;
                const float v = acc[mt][nt][r] + bb;
                if (hm) {
                    const size_t idx =
                        ((size_t)((row >> 10) * 16 + (col >> 6)) * 1024 +
                         (row & 1023)) * 64 + (col & 63);
                    dst[idx] = (bf16)v;
                } else {
                    const int vc = col - 1024;
                    const size_t idx =
                        ((size_t)((row >> 10) * 16 + (vc >> 6)) * 64 +
                         (vc & 63)) * 1024 + (row & 1023);
                    dst[idx] = (bf16)v;
                }
            }
        }
    }
}

// ---------------------------------------------------------------------------
// Output projection: 128x64 tile (BK=32, 4 waves 2x2, acc 4x2),
// triple-buffer counted-vmcnt schedule (R3-verified). XCD swizzle.
// ---------------------------------------------------------------------------
__global__ __launch_bounds__(256, 3) void ogemm_kernel(
    const bf16* __restrict__ Aw, const bf16* __restrict__ OWt,
    const float* __restrict__ o_b, float* __restrict__ C)
{
    __shared__ __align__(16) bf16 As[3][128][32];
    __shared__ __align__(16) bf16 Bs[3][64][32];

    const int t    = threadIdx.x;
    const int lane = t & 63;
    const int wave = t >> 6;
    const int wm   = wave & 1;
    const int wn   = wave >> 1;
    const int l15  = lane & 15;
    const int quad = lane >> 4;

    const int orig = blockIdx.y * 16 + blockIdx.x;
    const int wg   = (orig & 7) * 64 + (orig >> 3);
    const int by   = wg >> 4;
    const int bx   = wg & 15;

    const int gn0 = bx * 64;
    const int gm0 = by * 128;
    const int K   = 1024;

    const int srow    = lane >> 2;
    const int chunk_g = (lane & 3) ^ ((srow >> 1) & 3);
    const size_t aoff = (size_t)(gm0 + wave * 32 + srow) * K + chunk_g * 8;
    const size_t boff = (size_t)(gn0 + wave * 16 + srow) * K + chunk_g * 8;

    f32x4 acc[4][2];
    #pragma unroll
    for (int i = 0; i < 4; ++i)
        #pragma unroll
        for (int j = 0; j < 2; ++j)
            acc[i][j] = (f32x4){0.f, 0.f, 0.f, 0.f};

    #define OSTAGE(k0_, buf_)                                                          \
        {                                                                              \
            gload_lds16(Aw + aoff + (k0_),                  &As[buf_][wave * 32][0]);  \
            gload_lds16(Aw + aoff + (size_t)16 * K + (k0_), &As[buf_][wave * 32 + 16][0]); \
            gload_lds16(OWt + boff + (k0_),                 &Bs[buf_][wave * 16][0]);  \
        }

    #define OCOMPUTE(bufi)                                                             \
        {                                                                              \
            bf16x8 af[4], bfr[2];                                                      \
            _Pragma("unroll")                                                          \
            for (int mt = 0; mt < 4; ++mt) {                                           \
                const int row = wm * 64 + mt * 16 + l15;                               \
                af[mt] = *(const bf16x8*)(&As[bufi][row][(quad ^ ((row >> 1) & 3)) * 8]); \
            }                                                                          \
            _Pragma("unroll")                                                          \
            for (int nt = 0; nt < 2; ++nt) {                                           \
                const int row = wn * 32 + nt * 16 + l15;                               \
                bfr[nt] = *(const bf16x8*)(&Bs[bufi][row][(quad ^ ((row >> 1) & 3)) * 8]); \
            }                                                                          \
            __builtin_amdgcn_s_setprio(1);                                             \
            _Pragma("unroll")                                                          \
            for (int mt = 0; mt < 4; ++mt)                                             \
                _Pragma("unroll")                                                      \
                for (int nt = 0; nt < 2; ++nt)                                         \
                    acc[mt][nt] = mfma_16x16x32(af[mt], bfr[nt], acc[mt][nt]);         \
            __builtin_amdgcn_s_setprio(0);                                             \
        }

    OSTAGE(0, 0);
    OSTAGE(32, 1);
    int bc = 0, bn2 = 2;

    for (int k0 = 0; k0 < K - 64; k0 += 32) {
        OSTAGE(k0 + 64, bn2);
        SYNC_PRE(6);
        OCOMPUTE(bc);
        SYNC_POST();
        int nb = bc + 1;  if (nb == 3) nb = 0;
        int nn = bn2 + 1; if (nn == 3) nn = 0;
        bc = nb; bn2 = nn;
    }
    SYNC_PRE(3);
    OCOMPUTE(bc);
    SYNC_POST();
    bc = (bc + 1 == 3) ? 0 : bc + 1;
    SYNC_PRE(0);
    OCOMPUTE(bc);

    #undef OSTAGE
    #undef OCOMPUTE

    #pragma unroll
    for (int nt = 0; nt < 2; ++nt) {
        const int col = gn0 + wn * 32 + nt * 16 + l15;
        const float bb = o_b[col];
        #pragma unroll
        for (int mt = 0; mt < 4; ++mt) {
            #pragma unroll
            for (int r = 0; r < 4; ++r) {
                const int row = gm0 + wm * 64 + mt * 16 + quad * 4 + r;
                C[(size_t)row * 1024 + col] = acc[mt][nt][r] + bb;
            }
        }
    }
}

// ---------------------------------------------------------------------------
// Attention v7 (R3-verified, measured optimum of the attn design space:
// staged QBLK=128 ~33us < staged QBLK=64 44.9us < unstaged 66.5us).
// block = (head, 128 q-rows), 4 waves, wave owns 32 q over the FULL kv range.
// K/V^T chunks staged once per block into double-buffered LDS
// (global_load_lds, XOR unit-swizzle), shared by 4 waves; 1 barrier/chunk.
// p = __builtin_amdgcn_exp2f(s) (Q pre-scaled by 1/32*log2e).
// Row-sums via MFMA with an all-ones B.
// ---------------------------------------------------------------------------
__global__ __launch_bounds__(256) void attn_kernel(
    const bf16* __restrict__ Q, const bf16* __restrict__ K,
    const bf16* __restrict__ V, bf16* __restrict__ O)
{
    const int t    = threadIdx.x;
    const int lane = t & 63;
    const int wave = t >> 6;
    const int l15  = lane & 15;
    const int quad = lane >> 4;

    const int head = blockIdx.x;        // b*16 + h
    const int q0   = blockIdx.y * 128;
    const int b    = head >> 4;
    const int h    = head & 15;

    __shared__ __align__(16) bf16 Kb[2][64][64];   // [buf][kv][hd]
    __shared__ __align__(16) bf16 Vb[2][64][64];   // [buf][hd][kv]
    __shared__ __align__(16) bf16 P[4][32][72];    // per-wave P, pad 64->72

    const bf16* Qp  = Q + ((size_t)head * 1024 + q0 + wave * 32) * 64;
    const bf16* Kp  = K + (size_t)head * 1024 * 64;
    const bf16* Vtp = V + (size_t)head * 64 * 1024;

    const int r8  = lane >> 3;          // 0..7
    const int c8  = lane & 7;           // 0..7
    const int swz = (c8 ^ r8) * 8;      // fetch-side XOR unit swizzle

    bf16x8 aq[2][2];
    #pragma unroll
    for (int mt = 0; mt < 2; ++mt)
        #pragma unroll
        for (int kc = 0; kc < 2; ++kc)
            aq[mt][kc] = *(const bf16x8*)(Qp + (mt * 16 + l15) * 64 + kc * 32 + quad * 8);

    bf16x8 vones;
    #pragma unroll
    for (int j = 0; j < 8; ++j) vones[j] = (bf16)1.0f;

    f32x4 oacc[2][4];
    #pragma unroll
    for (int mt = 0; mt < 2; ++mt)
        #pragma unroll
        for (int nt = 0; nt < 4; ++nt)
            oacc[mt][nt] = (f32x4){0.f, 0.f, 0.f, 0.f};
    f32x4 lacc[2];
    lacc[0] = (f32x4){0.f, 0.f, 0.f, 0.f};
    lacc[1] = (f32x4){0.f, 0.f, 0.f, 0.f};

    #define STAGE(c, buf)                                                          \
        {                                                                          \
            const int kv0_ = (c) * 64;                                             \
            _Pragma("unroll")                                                      \
            for (int g = 0; g < 2; ++g) {                                          \
                const int R = wave * 16 + g * 8;                                   \
                gload_lds16(Kp + (size_t)(kv0_ + R + r8) * 64 + swz,               \
                            &Kb[buf][R][0]);                                       \
                gload_lds16(Vtp + (size_t)(R + r8) * 1024 + kv0_ + swz,            \
                            &Vb[buf][R][0]);                                       \
            }                                                                      \
        }

    STAGE(0, 0);

    const int sw = l15 & 7;             // read-side swizzle (row & 7)

    for (int c = 0; c < 16; ++c) {
        const int buf = c & 1;
        __syncthreads();
        if (c + 1 < 16) STAGE(c + 1, buf ^ 1);

        #pragma unroll
        for (int nt = 0; nt < 4; ++nt) {
            const bf16* krow = &Kb[buf][nt * 16 + l15][0];
            bf16x8 bk0 = *(const bf16x8*)(krow + (quad ^ sw) * 8);
            bf16x8 bk1 = *(const bf16x8*)(krow + ((quad + 4) ^ sw) * 8);
            #pragma unroll
            for (int mt = 0; mt < 2; ++mt) {
                f32x4 s = (f32x4){0.f, 0.f, 0.f, 0.f};
                s = mfma_16x16x32(aq[mt][0], bk0, s);
                s = mfma_16x16x32(aq[mt][1], bk1, s);
                #pragma unroll
                for (int r = 0; r < 4; ++r) {
                    const float e = __builtin_amdgcn_exp2f(s[r]);
                    P[wave][mt * 16 + quad * 4 + r][nt * 16 + l15] = (bf16)e;
                }
            }
        }

        #pragma unroll
        for (int mt = 0; mt < 2; ++mt) {
            bf16x8 pa0 = *(const bf16x8*)(&P[wave][mt * 16 + l15][quad * 8]);
            bf16x8 pa1 = *(const bf16x8*)(&P[wave][mt * 16 + l15][32 + quad * 8]);
            lacc[mt] = mfma_16x16x32(pa0, vones, lacc[mt]);
            lacc[mt] = mfma_16x16x32(pa1, vones, lacc[mt]);
            #pragma unroll
            for (int nt = 0; nt < 4; ++nt) {
                const bf16* vrow = &Vb[buf][nt * 16 + l15][0];
                bf16x8 bv0 = *(const bf16x8*)(vrow + (quad ^ sw) * 8);
                bf16x8 bv1 = *(const bf16x8*)(vrow + ((quad + 4) ^ sw) * 8);
                oacc[mt][nt] = mfma_16x16x32(pa0, bv0, oacc[mt][nt]);
                oacc[mt][nt] = mfma_16x16x32(pa1, bv1, oacc[mt][nt]);
            }
        }
    }
    #undef STAGE

    // lacc[mt][r] = row sum for row quad*4+r, replicated across all 16 cols
    #pragma unroll
    for (int mt = 0; mt < 2; ++mt) {
        const float invs[4] = {1.0f / lacc[mt][0], 1.0f / lacc[mt][1],
                               1.0f / lacc[mt][2], 1.0f / lacc[mt][3]};
        #pragma unroll
        for (int nt = 0; nt < 4; ++nt) {
            #pragma unroll
            for (int r = 0; r < 4; ++r) {
                const int row = q0 + wave * 32 + mt * 16 + quad * 4 + r;
                O[((size_t)b * 1024 + row) * 1024 + h * 64 + nt * 16 + l15] =
                    (bf16)(oacc[mt][nt][r] * invs[r]);
            }
        }
    }
}

// ---------------------------------------------------------------------------
// Host launcher — inputs/outputs FLOAT32 per reference; bf16 internal.
// ws (bf16 elems): l_bf 4M | v_bf 4M | QWt 1M | KVWt 2M | OWt 1M |
//                  Qh 4M | Kh 4M | Vt 4M | Aw 4M = 28M = 56 MB
// ---------------------------------------------------------------------------
extern "C" void kernel_launch(void* const* d_in, const int* in_sizes, int n_in,
                              void* d_out, int out_size, void* d_ws, size_t ws_size,
                              hipStream_t stream)
{
    const float* v_h = (const float*)d_in[0];
    const float* l_h = (const float*)d_in[1];
    const float* q_w = (const float*)d_in[2];
    const float* q_b = (const float*)d_in[3];
    const float* k_w = (const float*)d_in[4];
    const float* k_b = (const float*)d_in[5];
    const float* v_w = (const float*)d_in[6];
    const float* v_b = (const float*)d_in[7];
    const float* o_w = (const float*)d_in[8];
    const float* o_b = (const float*)d_in[9];
    float* out = (float*)d_out;

    const size_t SZ = (size_t)4096 * 1024;      // 4M
    const size_t WZ = (size_t)1024 * 1024;      // 1M

    bf16* l_bf = (bf16*)d_ws;
    bf16* v_bf = l_bf + SZ;
    bf16* QWt  = v_bf + SZ;
    bf16* KVWt = QWt + WZ;
    bf16* OWt  = KVWt + 2 * WZ;
    bf16* Qh   = OWt + WZ;      // (b,h,ls,64), pre-scaled by QSCALE
    bf16* Kh   = Qh + SZ;       // (b,h,vs,64)
    bf16* Vt   = Kh + SZ;       // (b,h,64,vs)
    bf16* Aw   = Vt + SZ;       // (b,ls,1024)

    prep_kernel<<<dim3(5120), 256, 0, stream>>>(
        l_h, v_h, q_w, k_w, v_w, o_w, l_bf, v_bf, QWt, KVWt, OWt);

    proj128_kernel<<<dim3(24, 32), 256, 0, stream>>>(
        l_bf, v_bf, QWt, KVWt, q_b, k_b, v_b, Qh, Kh, Vt);

    attn_kernel<<<dim3(64, 8), 256, 0, stream>>>(Qh, Kh, Vt, Aw);

    ogemm_kernel<<<dim3(16, 32), 256, 0, stream>>>(Aw, OWt, o_b, out);

    (void)in_sizes; (void)n_in; (void)out_size; (void)ws_size;
}